// Round 16
// baseline (257.703 us; speedup 1.0000x reference)
//
#include <hip/hip_runtime.h>
#include <math.h>

// TopKRouter: logits = rf @ gw^T, softmax, top-2, aux load-balance loss.
// rf: [16384, 4096] f32, gw: [64, 4096] f32.
// out (f32 flat): weights [0,32768) | indices-as-float [32768,65536) | aux [65536]
//
// R15: SINGLE-WAVE workgroups, zero hot-loop barriers, zero register staging.
// Block = 1 wave x 32 rows x full K (128 steps of 32k). Both operands stream
// through a private 4-slot LDS ring (12 KB/slot: A 4 KB source-swizzled +
// W frags 8 KB) via global_load_lds; counted s_waitcnt vmcnt(24) (~2.5-step
// lookahead, never 0 mid-loop). Operand roles swapped: W = MFMA A-operand
// (wsW layout is already expert-major frags), rf = B-operand. 24 MFMA
// (bf16-split 3-term) + 12 ds_read_b128 per step. Fused epilogue (lt overlays
// ring). W traffic halved vs R14 (512 waves x 1 MB); A = 256 MB at HBM rate.
// ws: [0,256) psum | [256,512) cnt | [512,516) flagcnt | [768,+32K) flaglist
//     | [1M, +1MB) W frag stream.

typedef __attribute__((ext_vector_type(8))) short bf16x8;
typedef __attribute__((ext_vector_type(4))) float f32x4;

constexpr int B_ROWS  = 16384;
constexpr int D_DIM   = 4096;
constexpr int E_EXP   = 64;
constexpr int NTHR    = 512;    // wsplit threads
constexpr int RPB     = 32;     // rows per block (1 wave)
constexpr int NS      = 128;    // K-steps (32 k each)
constexpr int SLOT    = 12288;  // ring slot bytes: A 4K + W 8K
constexpr int FLAGCAP = 8192;
constexpr float GAPTHR = 1e-3f;

__device__ __forceinline__ float wave_max64(float v) {
#pragma unroll
  for (int m = 32; m >= 1; m >>= 1) v = fmaxf(v, __shfl_xor(v, m, 64));
  return v;
}
__device__ __forceinline__ float wave_sum64(float v) {
#pragma unroll
  for (int m = 32; m >= 1; m >>= 1) v += __shfl_xor(v, m, 64);
  return v;
}
// argmax over 64 lanes; ties -> smaller index (matches jax.lax.top_k)
__device__ __forceinline__ void wave_argmax64(float v, int i, float& mv, int& mi) {
#pragma unroll
  for (int m = 32; m >= 1; m >>= 1) {
    float ov = __shfl_xor(v, m, 64);
    int   oi = __shfl_xor(i, m, 64);
    if (ov > v || (ov == v && oi < i)) { v = ov; i = oi; }
  }
  mv = v; mi = i;
}

__device__ __forceinline__ void async_copy16(void* lds_dst, const void* g_src) {
  auto g = (const __attribute__((address_space(1))) char*)(g_src);
  auto l = (__attribute__((address_space(3))) char*)(lds_dst);
  __builtin_amdgcn_global_load_lds(g, l, 16, 0, 0);
}

// trunc-split 8 fp32 -> hi/lo bf16 frags (f = hi + rem exactly at bf16 precision)
__device__ __forceinline__ void split8(const f32x4 a, const f32x4 b, bf16x8& hi, bf16x8& lo) {
  float f[8] = {a[0], a[1], a[2], a[3], b[0], b[1], b[2], b[3]};
#pragma unroll
  for (int i = 0; i < 8; ++i) {
    unsigned int u = __float_as_uint(f[i]);
    hi[i] = (short)(u >> 16);
    float rem = f[i] - __uint_as_float(u & 0xffff0000u);
    lo[i] = (short)(__float_as_uint(rem) >> 16);
  }
}

// W pre-split: gw [64][4096] f32 -> frag stream [n=k/32][er][h][lane][16B].
// Used as MFMA A-operand: lane l elem i <-> W[e=16*er+(l&15)][k=n*32+(l>>4)*8+i].
// Block 0 also zeroes the ws header (psum/cnt/flagcnt).
__global__ __launch_bounds__(NTHR) void wsplit(const float* __restrict__ gw,
                                               char* __restrict__ wsW,
                                               unsigned int* __restrict__ hdr) {
  const int n = blockIdx.x;          // 128 k-steps
  const int t = threadIdx.x;
  if (n == 0 && t < 192) hdr[t] = 0u;
  const int lane = t & 63, h = (t >> 6) & 1, er = t >> 7;
  const int e  = er * 16 + (lane & 15);
  const int k0 = n * 32 + (lane >> 4) * 8;
  const float* src = gw + (size_t)e * D_DIM + k0;
  union { unsigned short us[8]; uint4 v; } pk;
#pragma unroll
  for (int i = 0; i < 8; ++i) {
    float f = src[i];
    unsigned int u = __float_as_uint(f);
    if (h == 0) {
      pk.us[i] = (unsigned short)(u >> 16);
    } else {
      float rem = f - __uint_as_float(u & 0xffff0000u);
      pk.us[i] = (unsigned short)(__float_as_uint(rem) >> 16);
    }
  }
  *(uint4*)(wsW + (size_t)n * 8192 + (size_t)t * 16) = pk.v;
}

__global__ __launch_bounds__(64) void gemm_router(
    const float* __restrict__ rf, const char* __restrict__ wsW,
    float* __restrict__ out, float* __restrict__ psum,
    unsigned int* __restrict__ cnt, int* __restrict__ flagcnt,
    int* __restrict__ flaglist) {
  __shared__ char lds[4 * SLOT] __attribute__((aligned(16)));  // 48 KB ring

  const int lane = threadIdx.x;          // 64 threads = 1 wave
  const int row0 = blockIdx.x * RPB;

  // A staging map: instr j covers rows 8j..8j+7; lane -> row 8j+(lane>>3),
  // slot lane&7; LDS linear, source slot pre-swizzled (slot ^ row&7).
  int goffA[4];
#pragma unroll
  for (int j = 0; j < 4; ++j) {
    const int row = 8 * j + (lane >> 3);
    const int sl  = lane & 7;
    goffA[j] = (row0 + row) * D_DIM + ((sl ^ (row & 7)) << 2);  // float offset
  }

  // compute-side A (B-operand) read offsets: rr row-frags, slots s0,s0+1
  const int s0 = (lane >> 4) * 2;
  int aoff[2][2];
#pragma unroll
  for (int rr = 0; rr < 2; ++rr) {
    const int R = 16 * rr + (lane & 15);
    aoff[rr][0] = R * 128 + (((s0)     ^ (R & 7)) << 4);
    aoff[rr][1] = R * 128 + (((s0 + 1) ^ (R & 7)) << 4);
  }

  f32x4 acc[8] = {{0.f,0.f,0.f,0.f},{0.f,0.f,0.f,0.f},{0.f,0.f,0.f,0.f},{0.f,0.f,0.f,0.f},
                  {0.f,0.f,0.f,0.f},{0.f,0.f,0.f,0.f},{0.f,0.f,0.f,0.f},{0.f,0.f,0.f,0.f}};

#define ISSUE(nn)                                                             \
  {                                                                           \
    char* b_ = lds + ((nn) & 3) * SLOT;                                       \
    _Pragma("unroll") for (int j = 0; j < 4; ++j)                             \
      async_copy16(b_ + (j * 64 + lane) * 16, rf + goffA[j] + (nn) * 32);     \
    _Pragma("unroll") for (int j = 0; j < 8; ++j)                             \
      async_copy16(b_ + 4096 + (j * 64 + lane) * 16,                          \
                   wsW + (size_t)(nn) * 8192 + (j * 64 + lane) * 16);         \
  }

#define STEP(nn)                                                              \
  {                                                                           \
    const char* ab = lds + ((nn) & 3) * SLOT;                                 \
    bf16x8 bhi0, blo0, bhi1, blo1;                                            \
    {                                                                         \
      f32x4 fl = *(const f32x4*)(ab + aoff[0][0]);                            \
      f32x4 fh = *(const f32x4*)(ab + aoff[0][1]);                            \
      split8(fl, fh, bhi0, blo0);                                             \
    }                                                                         \
    {                                                                         \
      f32x4 fl = *(const f32x4*)(ab + aoff[1][0]);                            \
      f32x4 fh = *(const f32x4*)(ab + aoff[1][1]);                            \
      split8(fl, fh, bhi1, blo1);                                             \
    }                                                                         \
    _Pragma("unroll") for (int er = 0; er < 4; ++er) {                        \
      const bf16x8 whi = *(const bf16x8*)(ab + 4096 + er * 2048 + lane * 16); \
      const bf16x8 wlo = *(const bf16x8*)(ab + 4096 + er * 2048 + 1024 + lane * 16); \
      acc[er*2+0] = __builtin_amdgcn_mfma_f32_16x16x32_bf16(whi, bhi0, acc[er*2+0], 0, 0, 0); \
      acc[er*2+0] = __builtin_amdgcn_mfma_f32_16x16x32_bf16(wlo, bhi0, acc[er*2+0], 0, 0, 0); \
      acc[er*2+0] = __builtin_amdgcn_mfma_f32_16x16x32_bf16(whi, blo0, acc[er*2+0], 0, 0, 0); \
      acc[er*2+1] = __builtin_amdgcn_mfma_f32_16x16x32_bf16(whi, bhi1, acc[er*2+1], 0, 0, 0); \
      acc[er*2+1] = __builtin_amdgcn_mfma_f32_16x16x32_bf16(wlo, bhi1, acc[er*2+1], 0, 0, 0); \
      acc[er*2+1] = __builtin_amdgcn_mfma_f32_16x16x32_bf16(whi, blo1, acc[er*2+1], 0, 0, 0); \
    }                                                                         \
  }

  ISSUE(0); ISSUE(1); ISSUE(2);
  for (int n = 0; n < NS - 3; ++n) {                   // n = 0..124
    asm volatile("s_waitcnt vmcnt(24)" ::: "memory");  // step n resident
    __builtin_amdgcn_sched_barrier(0);
    STEP(n);
    ISSUE(n + 3);
  }
  asm volatile("s_waitcnt vmcnt(24)" ::: "memory");
  __builtin_amdgcn_sched_barrier(0);
  STEP(NS - 3);
  asm volatile("s_waitcnt vmcnt(12)" ::: "memory");
  __builtin_amdgcn_sched_barrier(0);
  STEP(NS - 2);
  asm volatile("s_waitcnt vmcnt(0)" ::: "memory");
  __builtin_amdgcn_sched_barrier(0);
  STEP(NS - 1);
#undef ISSUE
#undef STEP

  // epilogue: overlay logits tile on the ring (all loads/reads drained)
  asm volatile("s_waitcnt vmcnt(0) lgkmcnt(0)" ::: "memory");
  __builtin_amdgcn_sched_barrier(0);
  float* lt = (float*)lds;   // [32][65]
  // D frag (A=W, B=rf): col(lane&15)=rf-row-in-frag, row((lane>>4)*4+j)=expert-in-frag
#pragma unroll
  for (int er = 0; er < 4; ++er)
#pragma unroll
    for (int rr = 0; rr < 2; ++rr)
#pragma unroll
      for (int j = 0; j < 4; ++j)
        lt[(16 * rr + (lane & 15)) * 65 + 16 * er + (lane >> 4) * 4 + j] = acc[er * 2 + rr][j];

  float Pacc = 0.f;
  int myCnt = 0;
  for (int r = 0; r < RPB; ++r) {
    const float lg = lt[r * 65 + lane];
    const float m  = wave_max64(lg);
    const float p  = __expf(lg - m);
    const float ss = wave_sum64(p);
    Pacc += p / ss;
    float v1; int i1; wave_argmax64(lg, lane, v1, i1);
    const float lm1 = (lane == i1) ? -INFINITY : lg;
    float v2; int i2; wave_argmax64(lm1, lane, v2, i2);
    const float lm2 = (lane == i2) ? -INFINITY : lm1;
    float v3; int i3; wave_argmax64(lm2, lane, v3, i3);
    myCnt += (lane == i1) + (lane == i2);
    if (lane == 0) {
      const float ex = expf(v2 - v1);
      const int row = row0 + r;
      out[row * 2 + 0] = 1.f / (1.f + ex);
      out[row * 2 + 1] = ex / (1.f + ex);
      out[2 * B_ROWS + row * 2 + 0] = (float)i1;
      out[2 * B_ROWS + row * 2 + 1] = (float)i2;
      if (v1 - v2 < GAPTHR || v2 - v3 < GAPTHR) {
        int fi = atomicAdd(flagcnt, 1);
        if (fi < FLAGCAP) flaglist[fi] = row;
      }
    }
  }
  atomicAdd(&psum[lane], Pacc);
  if (myCnt) atomicAdd(&cnt[lane], (unsigned int)myCnt);
}

// exact fp64 recompute of flagged (near-tie) rows; block 0 also computes aux.
__global__ __launch_bounds__(256) void cleanup(
    const float* __restrict__ rf, const float* __restrict__ gw,
    const int* __restrict__ flagcnt, const int* __restrict__ flaglist,
    const float* __restrict__ psum, const unsigned int* __restrict__ cnt,
    float* __restrict__ out) {
  __shared__ double sm[256];
  const int t = threadIdx.x;
  if (blockIdx.x == 0 && t < 64) {
    const float f = (float)cnt[t] / (float)(B_ROWS * 2);
    const float P = psum[t] / (float)B_ROWS;
    float v = wave_sum64(f * P);
    if (t == 0) out[4 * B_ROWS] = (float)E_EXP * v;
  }
  const int nf = min(*flagcnt, FLAGCAP);
  for (int fi = blockIdx.x; fi < nf; fi += gridDim.x) {
    const int row = flaglist[fi];
    const int e = t & 63, seg = t >> 6;
    const float* a = rf + (size_t)row * D_DIM + seg * 1024;
    const float* w = gw + (size_t)e * D_DIM + seg * 1024;
    double p0 = 0.0, p1 = 0.0, p2 = 0.0, p3 = 0.0;
    for (int k = 0; k < 1024; k += 4) {
      p0 = fma((double)a[k + 0], (double)w[k + 0], p0);
      p1 = fma((double)a[k + 1], (double)w[k + 1], p1);
      p2 = fma((double)a[k + 2], (double)w[k + 2], p2);
      p3 = fma((double)a[k + 3], (double)w[k + 3], p3);
    }
    sm[t] = (p0 + p1) + (p2 + p3);
    __syncthreads();
    if (t < 64) {
      const double l = sm[t] + sm[64 + t] + sm[128 + t] + sm[192 + t];
      double v = l; int ii = t;
#pragma unroll
      for (int m = 32; m >= 1; m >>= 1) {
        double ov = __shfl_xor(v, m, 64); int oi = __shfl_xor(ii, m, 64);
        if (ov > v || (ov == v && oi < ii)) { v = ov; ii = oi; }
      }
      const double v1 = v; const int i1 = ii;
      const double lm = (t == i1) ? -1e300 : l;
      v = lm; ii = t;
#pragma unroll
      for (int m = 32; m >= 1; m >>= 1) {
        double ov = __shfl_xor(v, m, 64); int oi = __shfl_xor(ii, m, 64);
        if (ov > v || (ov == v && oi < ii)) { v = ov; ii = oi; }
      }
      const double v2 = v; const int i2 = ii;
      if (t == 0) {
        const double ex = exp(v2 - v1);
        out[row * 2 + 0] = (float)(1.0 / (1.0 + ex));
        out[row * 2 + 1] = (float)(ex / (1.0 + ex));
        out[2 * B_ROWS + row * 2 + 0] = (float)i1;
        out[2 * B_ROWS + row * 2 + 1] = (float)i2;
      }
    }
    __syncthreads();
  }
}

extern "C" void kernel_launch(void* const* d_in, const int* in_sizes, int n_in,
                              void* d_out, int out_size, void* d_ws, size_t ws_size,
                              hipStream_t stream) {
  const float* rf = (const float*)d_in[0];
  const float* gw = (const float*)d_in[1];
  float* out = (float*)d_out;
  float* psum = (float*)d_ws;
  unsigned int* cnt = (unsigned int*)((char*)d_ws + 256);
  int* flagcnt = (int*)((char*)d_ws + 512);
  int* flaglist = (int*)((char*)d_ws + 768);
  char* wsW = (char*)d_ws + (1u << 20);

  wsplit<<<D_DIM / 32, NTHR, 0, stream>>>(gw, wsW, (unsigned int*)d_ws);
  gemm_router<<<B_ROWS / RPB, 64, 0, stream>>>(rf, wsW, out, psum, cnt,
                                               flagcnt, flaglist);
  cleanup<<<64, 256, 0, stream>>>(rf, gw, flagcnt, flaglist, psum, cnt, out);
}

// Round 17
// 257.549 us; speedup vs baseline: 1.0006x; 1.0006x over previous
//
#include <hip/hip_runtime.h>
#include <math.h>

// TopKRouter: logits = rf @ gw^T, softmax, top-2, aux load-balance loss.
// rf: [16384, 4096] f32, gw: [64, 4096] f32.
// out (f32 flat): weights [0,32768) | indices-as-float [32768,65536) | aux [65536]
//
// R16: LONG-RUN staging. Evidence: R7-R15 all converge to ~1.7 TB/s rf reads
// (128B-per-row scattered chunks, ~25% DRAM page efficiency) while streaming
// kernels hit 6.8 TB/s. Here each gload_lds instruction covers ONE ROW'S
// CONTIGUOUS 1 KB, rows consumed sequentially. Block = 16 rows x 256 thr
// (4 waves; wave = 16 experts). A: 2 ring panels [16 rows][1KB] (swizzled in
// 128B groups); W: 4-slot 8KB frag ring. 8 sub-steps/panel, derived vmcnt
// literals, barrier per sub-step, lookahead >> latency. LDS 64KB -> 2
// blocks/CU. bf16-split 3-term MFMA; fused epilogue; fp64 tie cleanup.
// ws: [0,256) psum | [256,512) cnt | [512,516) flagcnt | [768,+32K) flaglist
//     | [1M, +1MB) W frag stream.

typedef __attribute__((ext_vector_type(8))) short bf16x8;
typedef __attribute__((ext_vector_type(4))) float f32x4;

constexpr int B_ROWS  = 16384;
constexpr int D_DIM   = 4096;
constexpr int E_EXP   = 64;
constexpr int NTHR    = 512;    // wsplit threads
constexpr int GTHR    = 256;    // gemm threads (4 waves)
constexpr int TM      = 16;     // rows per block
constexpr int NPAN    = 16;     // A panels of 256 k each
constexpr int FLAGCAP = 8192;
constexpr float GAPTHR = 1e-3f;

__device__ __forceinline__ float wave_max64(float v) {
#pragma unroll
  for (int m = 32; m >= 1; m >>= 1) v = fmaxf(v, __shfl_xor(v, m, 64));
  return v;
}
__device__ __forceinline__ float wave_sum64(float v) {
#pragma unroll
  for (int m = 32; m >= 1; m >>= 1) v += __shfl_xor(v, m, 64);
  return v;
}
// argmax over 64 lanes; ties -> smaller index (matches jax.lax.top_k)
__device__ __forceinline__ void wave_argmax64(float v, int i, float& mv, int& mi) {
#pragma unroll
  for (int m = 32; m >= 1; m >>= 1) {
    float ov = __shfl_xor(v, m, 64);
    int   oi = __shfl_xor(i, m, 64);
    if (ov > v || (ov == v && oi < i)) { v = ov; i = oi; }
  }
  mv = v; mi = i;
}

__device__ __forceinline__ void async_copy16(void* lds_dst, const void* g_src) {
  auto g = (const __attribute__((address_space(1))) char*)(g_src);
  auto l = (__attribute__((address_space(3))) char*)(lds_dst);
  __builtin_amdgcn_global_load_lds(g, l, 16, 0, 0);
}

// trunc-split 8 fp32 -> hi/lo bf16 frags (f = hi + rem exactly at bf16 precision)
__device__ __forceinline__ void split8(const f32x4 a, const f32x4 b, bf16x8& hi, bf16x8& lo) {
  float f[8] = {a[0], a[1], a[2], a[3], b[0], b[1], b[2], b[3]};
#pragma unroll
  for (int i = 0; i < 8; ++i) {
    unsigned int u = __float_as_uint(f[i]);
    hi[i] = (short)(u >> 16);
    float rem = f[i] - __uint_as_float(u & 0xffff0000u);
    lo[i] = (short)(__float_as_uint(rem) >> 16);
  }
}

// W pre-split: gw [64][4096] f32 -> frag stream [n=k/32][cb][h][lane][16B].
// B-frag (mfma_f32_16x16x32_bf16): lane l elem i <-> B[k=(l>>4)*8+i][col=l&15].
// Block 0 also zeroes the ws header (psum/cnt/flagcnt).
__global__ __launch_bounds__(NTHR) void wsplit(const float* __restrict__ gw,
                                               char* __restrict__ wsW,
                                               unsigned int* __restrict__ hdr) {
  const int n = blockIdx.x;          // 128 k-steps
  const int t = threadIdx.x;
  if (n == 0 && t < 192) hdr[t] = 0u;
  const int lane = t & 63, h = (t >> 6) & 1, wc = t >> 7;
  const int col = wc * 16 + (lane & 15);
  const int k0  = n * 32 + (lane >> 4) * 8;
  const float* src = gw + (size_t)col * D_DIM + k0;
  union { unsigned short us[8]; uint4 v; } pk;
#pragma unroll
  for (int i = 0; i < 8; ++i) {
    float f = src[i];
    unsigned int u = __float_as_uint(f);
    if (h == 0) {
      pk.us[i] = (unsigned short)(u >> 16);
    } else {
      float rem = f - __uint_as_float(u & 0xffff0000u);
      pk.us[i] = (unsigned short)(__float_as_uint(rem) >> 16);
    }
  }
  *(uint4*)(wsW + (size_t)n * 8192 + (size_t)t * 16) = pk.v;
}

__global__ __launch_bounds__(GTHR) void gemm_router(
    const float* __restrict__ rf, const char* __restrict__ wsW,
    float* __restrict__ out, float* __restrict__ psum,
    unsigned int* __restrict__ cnt, int* __restrict__ flagcnt,
    int* __restrict__ flaglist) {
  // A panels: 2 x 16KB @0; W slots: 4 x 8KB @32768. 64KB -> 2 blocks/CU.
  __shared__ char lds[65536] __attribute__((aligned(16)));
  __shared__ float pP[4][E_EXP];
  __shared__ unsigned int scnt[E_EXP];

  const int t = threadIdx.x, lane = t & 63, wv = t >> 6;
  const int row0 = blockIdx.x * TM;

  // A staging: panel = [16 rows][64 slots x 16B]; load j covers q=j*256+t;
  // one wave (64 consecutive q) = one row's full 1KB (long DRAM run).
  // LDS linear; source slot low-3 bits pre-XORed with row&7 (both-sides swz).
  int goffA[4];
#pragma unroll
  for (int j = 0; j < 4; ++j) {
    const int q = j * GTHR + t;
    const int row = q >> 6, ls = q & 63;
    const int gs = (ls & ~7) | ((ls & 7) ^ (row & 7));
    goffA[j] = (row0 + row) * D_DIM + gs * 4;   // float offset; + panel*256
  }

  f32x4 acc = {0.f, 0.f, 0.f, 0.f};

#define ISSUE_A(pan, sa)                                                      \
  {                                                                           \
    char* ad_ = lds + (sa) * 16384;                                           \
    _Pragma("unroll") for (int j = 0; j < 4; ++j)                             \
      async_copy16(ad_ + (j * GTHR + t) * 16, rf + goffA[j] + (pan) * 256);   \
  }
#define ISSUE_W(mm)                                                           \
  {                                                                           \
    char* wd_ = lds + 32768 + ((mm) & 3) * 8192;                              \
    _Pragma("unroll") for (int j = 0; j < 2; ++j)                             \
      async_copy16(wd_ + (j * GTHR + t) * 16,                                 \
                   wsW + (size_t)(mm) * 8192 + (j * GTHR + t) * 16);          \
  }

#define PANEL(p, SA, LASTP)                                                   \
  {                                                                           \
    _Pragma("unroll")                                                         \
    for (int s = 0; s < 8; ++s) {                                             \
      if (LASTP) {                                                            \
        if (s < 6)       asm volatile("s_waitcnt vmcnt(4)" ::: "memory");     \
        else if (s == 6) asm volatile("s_waitcnt vmcnt(2)" ::: "memory");     \
        else             asm volatile("s_waitcnt vmcnt(0)" ::: "memory");     \
      } else {                                                                \
        if (s == 1 || s == 2) asm volatile("s_waitcnt vmcnt(8)" ::: "memory");\
        else                  asm volatile("s_waitcnt vmcnt(4)" ::: "memory");\
      }                                                                       \
      __builtin_amdgcn_s_barrier();                                           \
      __builtin_amdgcn_sched_barrier(0);                                      \
      const int m = (p) * 8 + s;                                              \
      if (!(LASTP) && s == 0) ISSUE_A((p) + 1, (SA) ^ 1);                     \
      if (!(LASTP) || s < 5) ISSUE_W(m + 3);                                  \
      const char* ab = lds + (SA) * 16384 + (lane & 15) * 1024;               \
      const int sl0 = s * 8 + (((lane >> 4) * 2 + 0) ^ (lane & 7));           \
      const int sl1 = s * 8 + (((lane >> 4) * 2 + 1) ^ (lane & 7));           \
      f32x4 fa = *(const f32x4*)(ab + sl0 * 16);                              \
      f32x4 fb = *(const f32x4*)(ab + sl1 * 16);                              \
      bf16x8 ahi, alo;                                                        \
      split8(fa, fb, ahi, alo);                                               \
      const char* wb = lds + 32768 + (m & 3) * 8192 + wv * 2048 + lane * 16;  \
      const bf16x8 whi = *(const bf16x8*)(wb);                                \
      const bf16x8 wlo = *(const bf16x8*)(wb + 1024);                         \
      acc = __builtin_amdgcn_mfma_f32_16x16x32_bf16(ahi, whi, acc, 0, 0, 0);  \
      acc = __builtin_amdgcn_mfma_f32_16x16x32_bf16(alo, whi, acc, 0, 0, 0);  \
      acc = __builtin_amdgcn_mfma_f32_16x16x32_bf16(ahi, wlo, acc, 0, 0, 0);  \
    }                                                                         \
  }

  // prologue: A(0) oldest, then W(0..2)
  ISSUE_A(0, 0);
  ISSUE_W(0); ISSUE_W(1); ISSUE_W(2);

  for (int p = 0; p < NPAN - 2; p += 2) {
    PANEL(p, 0, false);
    PANEL(p + 1, 1, false);
  }
  PANEL(NPAN - 2, 0, false);
  PANEL(NPAN - 1, 1, true);
#undef PANEL
#undef ISSUE_A
#undef ISSUE_W

  // epilogue: logits tile overlays A slot0 (panel 15 used slot1; safe)
  float* lt = (float*)lds;   // [16][65]
  if (t < E_EXP) scnt[t] = 0;
#pragma unroll
  for (int j = 0; j < 4; ++j)
    lt[((lane >> 4) * 4 + j) * 65 + wv * 16 + (lane & 15)] = acc[j];
  __syncthreads();

  // wave wv handles rows wv*4 .. +4; lane = expert
  float Pacc = 0.f;
#pragma unroll
  for (int jr = 0; jr < 4; ++jr) {
    const int r = wv * 4 + jr;
    const float lg = lt[r * 65 + lane];
    const float mx = wave_max64(lg);
    const float pe = __expf(lg - mx);
    const float ss = wave_sum64(pe);
    Pacc += pe / ss;
    float v1; int i1; wave_argmax64(lg, lane, v1, i1);
    const float lm1 = (lane == i1) ? -INFINITY : lg;
    float v2; int i2; wave_argmax64(lm1, lane, v2, i2);
    const float lm2 = (lane == i2) ? -INFINITY : lm1;
    float v3; int i3; wave_argmax64(lm2, lane, v3, i3);
    if (lane == 0) {
      const float ex = expf(v2 - v1);
      const int row = row0 + r;
      out[row * 2 + 0] = 1.f / (1.f + ex);
      out[row * 2 + 1] = ex / (1.f + ex);
      out[2 * B_ROWS + row * 2 + 0] = (float)i1;
      out[2 * B_ROWS + row * 2 + 1] = (float)i2;
      atomicAdd(&scnt[i1], 1u);
      atomicAdd(&scnt[i2], 1u);
      if (v1 - v2 < GAPTHR || v2 - v3 < GAPTHR) {
        int fi = atomicAdd(flagcnt, 1);
        if (fi < FLAGCAP) flaglist[fi] = row;
      }
    }
  }
  pP[wv][lane] = Pacc;
  __syncthreads();
  if (t < E_EXP) {
    atomicAdd(&psum[t], pP[0][t] + pP[1][t] + pP[2][t] + pP[3][t]);
    const unsigned int c = scnt[t];
    if (c) atomicAdd(&cnt[t], c);
  }
}

// exact fp64 recompute of flagged (near-tie) rows; block 0 also computes aux.
__global__ __launch_bounds__(256) void cleanup(
    const float* __restrict__ rf, const float* __restrict__ gw,
    const int* __restrict__ flagcnt, const int* __restrict__ flaglist,
    const float* __restrict__ psum, const unsigned int* __restrict__ cnt,
    float* __restrict__ out) {
  __shared__ double sm[256];
  const int t = threadIdx.x;
  if (blockIdx.x == 0 && t < 64) {
    const float f = (float)cnt[t] / (float)(B_ROWS * 2);
    const float P = psum[t] / (float)B_ROWS;
    float v = wave_sum64(f * P);
    if (t == 0) out[4 * B_ROWS] = (float)E_EXP * v;
  }
  const int nf = min(*flagcnt, FLAGCAP);
  for (int fi = blockIdx.x; fi < nf; fi += gridDim.x) {
    const int row = flaglist[fi];
    const int e = t & 63, seg = t >> 6;
    const float* a = rf + (size_t)row * D_DIM + seg * 1024;
    const float* w = gw + (size_t)e * D_DIM + seg * 1024;
    double p0 = 0.0, p1 = 0.0, p2 = 0.0, p3 = 0.0;
    for (int k = 0; k < 1024; k += 4) {
      p0 = fma((double)a[k + 0], (double)w[k + 0], p0);
      p1 = fma((double)a[k + 1], (double)w[k + 1], p1);
      p2 = fma((double)a[k + 2], (double)w[k + 2], p2);
      p3 = fma((double)a[k + 3], (double)w[k + 3], p3);
    }
    sm[t] = (p0 + p1) + (p2 + p3);
    __syncthreads();
    if (t < 64) {
      const double l = sm[t] + sm[64 + t] + sm[128 + t] + sm[192 + t];
      double v = l; int ii = t;
#pragma unroll
      for (int m = 32; m >= 1; m >>= 1) {
        double ov = __shfl_xor(v, m, 64); int oi = __shfl_xor(ii, m, 64);
        if (ov > v || (ov == v && oi < ii)) { v = ov; ii = oi; }
      }
      const double v1 = v; const int i1 = ii;
      const double lm = (t == i1) ? -1e300 : l;
      v = lm; ii = t;
#pragma unroll
      for (int m = 32; m >= 1; m >>= 1) {
        double ov = __shfl_xor(v, m, 64); int oi = __shfl_xor(ii, m, 64);
        if (ov > v || (ov == v && oi < ii)) { v = ov; ii = oi; }
      }
      const double v2 = v; const int i2 = ii;
      if (t == 0) {
        const double ex = exp(v2 - v1);
        out[row * 2 + 0] = (float)(1.0 / (1.0 + ex));
        out[row * 2 + 1] = (float)(ex / (1.0 + ex));
        out[2 * B_ROWS + row * 2 + 0] = (float)i1;
        out[2 * B_ROWS + row * 2 + 1] = (float)i2;
      }
    }
    __syncthreads();
  }
}

extern "C" void kernel_launch(void* const* d_in, const int* in_sizes, int n_in,
                              void* d_out, int out_size, void* d_ws, size_t ws_size,
                              hipStream_t stream) {
  const float* rf = (const float*)d_in[0];
  const float* gw = (const float*)d_in[1];
  float* out = (float*)d_out;
  float* psum = (float*)d_ws;
  unsigned int* cnt = (unsigned int*)((char*)d_ws + 256);
  int* flagcnt = (int*)((char*)d_ws + 512);
  int* flaglist = (int*)((char*)d_ws + 768);
  char* wsW = (char*)d_ws + (1u << 20);

  wsplit<<<D_DIM / 32, NTHR, 0, stream>>>(gw, wsW, (unsigned int*)d_ws);
  gemm_router<<<B_ROWS / TM, GTHR, 0, stream>>>(rf, wsW, out, psum, cnt,
                                                flagcnt, flaglist);
  cleanup<<<64, 256, 0, stream>>>(rf, gw, flagcnt, flaglist, psum, cnt, out);
}

// Round 19
// 223.664 us; speedup vs baseline: 1.1522x; 1.1515x over previous
//
#include <hip/hip_runtime.h>
#include <math.h>

// TopKRouter: logits = rf @ gw^T, softmax, top-2, aux load-balance loss.
// rf: [16384, 4096] f32, gw: [64, 4096] f32.
// out (f32 flat): weights [0,32768) | indices-as-float [32768,65536) | aux [65536]
//
// R18 = R17 (W-in-registers, 8-way split-K, A panel ring, 64 MB W traffic)
// + RACE FIX: R17's cross-wave lt combine used raw s_barrier with NO lgkmcnt
// drain -> other waves could read lt before the ds_writes landed (indices
// absmax 55). Fix: asm "s_waitcnt lgkmcnt(0)" (+"memory" clobber) before each
// combine barrier. LDS drains are ~tens of cycles; global prefetch (vmcnt)
// stays in flight, preserving the pipeline.
// ws: [0,256) psum | [256,512) cnt | [512,516) flagcnt | [768,+32K) flaglist
//     | [1M, +1MB) W frag stream | [2M, +32MB) partials.

typedef __attribute__((ext_vector_type(8))) short bf16x8;
typedef __attribute__((ext_vector_type(4))) float f32x4;

constexpr int B_ROWS  = 16384;
constexpr int D_DIM   = 4096;
constexpr int E_EXP   = 64;
constexpr int NTHR    = 512;              // wsplit/epilogue threads
constexpr int GTHR    = 512;              // gemm threads (8 waves)
constexpr int KSEG    = 512;              // k-range per block
constexpr int NSPLIT  = D_DIM / KSEG;     // 8
constexpr int PROWS   = 16;               // rows per panel
constexpr int NPANEL  = 16;               // panels per block (256 rows)
constexpr int FLAGCAP = 8192;
constexpr float GAPTHR = 1e-3f;

__device__ __forceinline__ float wave_max64(float v) {
#pragma unroll
  for (int m = 32; m >= 1; m >>= 1) v = fmaxf(v, __shfl_xor(v, m, 64));
  return v;
}
__device__ __forceinline__ float wave_sum64(float v) {
#pragma unroll
  for (int m = 32; m >= 1; m >>= 1) v += __shfl_xor(v, m, 64);
  return v;
}
// argmax over 64 lanes; ties -> smaller index (matches jax.lax.top_k)
__device__ __forceinline__ void wave_argmax64(float v, int i, float& mv, int& mi) {
#pragma unroll
  for (int m = 32; m >= 1; m >>= 1) {
    float ov = __shfl_xor(v, m, 64);
    int   oi = __shfl_xor(i, m, 64);
    if (ov > v || (ov == v && oi < i)) { v = ov; i = oi; }
  }
  mv = v; mi = i;
}

__device__ __forceinline__ void async_copy16(void* lds_dst, const void* g_src) {
  auto g = (const __attribute__((address_space(1))) char*)(g_src);
  auto l = (__attribute__((address_space(3))) char*)(lds_dst);
  __builtin_amdgcn_global_load_lds(g, l, 16, 0, 0);
}

// trunc-split 8 fp32 -> hi/lo bf16 frags (f = hi + rem exactly at bf16 precision)
__device__ __forceinline__ void split8(const f32x4 a, const f32x4 b, bf16x8& hi, bf16x8& lo) {
  float f[8] = {a[0], a[1], a[2], a[3], b[0], b[1], b[2], b[3]};
#pragma unroll
  for (int i = 0; i < 8; ++i) {
    unsigned int u = __float_as_uint(f[i]);
    hi[i] = (short)(u >> 16);
    float rem = f[i] - __uint_as_float(u & 0xffff0000u);
    lo[i] = (short)(__float_as_uint(rem) >> 16);
  }
}

// W pre-split: gw [64][4096] f32 -> frag stream [n=k/32][cb][h][lane][16B].
// B-frag (mfma_f32_16x16x32_bf16): lane l elem i <-> B[k=(l>>4)*8+i][col=l&15].
// Block 0 also zeroes the ws header (psum/cnt/flagcnt).
__global__ __launch_bounds__(NTHR) void wsplit(const float* __restrict__ gw,
                                               char* __restrict__ wsW,
                                               unsigned int* __restrict__ hdr) {
  const int n = blockIdx.x;          // 128 k-steps
  const int t = threadIdx.x;
  if (n == 0 && t < 192) hdr[t] = 0u;
  const int lane = t & 63, h = (t >> 6) & 1, wc = t >> 7;
  const int col = wc * 16 + (lane & 15);
  const int k0  = n * 32 + (lane >> 4) * 8;
  const float* src = gw + (size_t)col * D_DIM + k0;
  union { unsigned short us[8]; uint4 v; } pk;
#pragma unroll
  for (int i = 0; i < 8; ++i) {
    float f = src[i];
    unsigned int u = __float_as_uint(f);
    if (h == 0) {
      pk.us[i] = (unsigned short)(u >> 16);
    } else {
      float rem = f - __uint_as_float(u & 0xffff0000u);
      pk.us[i] = (unsigned short)(__float_as_uint(rem) >> 16);
    }
  }
  *(uint4*)(wsW + (size_t)n * 8192 + (size_t)t * 16) = pk.v;
}

__global__ __launch_bounds__(GTHR) void gemm_partial(
    const float* __restrict__ rf, const char* __restrict__ wsW,
    float* __restrict__ part) {
  __shared__ char apan[2][32768] __attribute__((aligned(16)));  // A dbuf panels
  __shared__ float lt[PROWS][E_EXP + 1];                        // combine tile

  const int t = threadIdx.x, lane = t & 63, wv = t >> 6;
  const int cb = wv & 3, ksub = wv >> 2;
  const int kseg = blockIdx.x & 7, rblk = blockIdx.x >> 3;  // 8 ksegs x 64 rblks
  const int row_base = rblk * (PROWS * NPANEL);             // 256 rows per block

  // ---- W frags resident in registers: 8 steps x hi/lo (64 VGPR) ----
  bf16x8 wh[8], wl[8];
  {
    const char* wp = wsW + (size_t)(kseg * 16 + ksub * 8) * 8192
                   + cb * 2048 + lane * 16;
#pragma unroll
    for (int s = 0; s < 8; ++s) {
      wh[s] = *(const bf16x8*)(wp + (size_t)s * 8192);
      wl[s] = *(const bf16x8*)(wp + (size_t)s * 8192 + 1024);
    }
  }
  __builtin_amdgcn_sched_barrier(0);   // pin W loads early (oldest in vmcnt)

  // ---- A staging map: panel = [16 rows][128 slots x 16B] (2 KB/row);
  // wave-instr = 1 KB contiguous source run; source slot pre-swizzled. ----
  int goffA[4];
#pragma unroll
  for (int j = 0; j < 4; ++j) {
    const int q = j * GTHR + t;         // 0..2047
    const int row = q >> 7, sl = q & 127;
    const int gs = (sl & ~7) | ((sl & 7) ^ (row & 7));
    goffA[j] = (row_base + row) * D_DIM + kseg * KSEG + gs * 4;
  }

  const int R = lane & 15;              // my A-frag row within panel

#define ISSUE(p)                                                             \
  {                                                                          \
    char* d_ = apan[(p) & 1];                                                \
    _Pragma("unroll") for (int j = 0; j < 4; ++j)                            \
      async_copy16(d_ + (j * GTHR + t) * 16,                                 \
                   rf + goffA[j] + (p) * (PROWS * D_DIM));                   \
  }
#define LGKM0 asm volatile("s_waitcnt lgkmcnt(0)" ::: "memory")

  ISSUE(0);
  for (int p = 0; p < NPANEL; ++p) {
    if (p + 1 < NPANEL) {
      ISSUE(p + 1);
      asm volatile("s_waitcnt vmcnt(4)" ::: "memory");  // panel p resident
    } else {
      asm volatile("s_waitcnt vmcnt(0)" ::: "memory");
    }
    __builtin_amdgcn_s_barrier();                       // (1) panel p ready

    f32x4 acc = {0.f, 0.f, 0.f, 0.f};
    const char* ab = apan[p & 1] + R * 2048;
#pragma unroll
    for (int s = 0; s < 8; ++s) {
      const int l0 = ksub * 64 + s * 8 + (lane >> 4) * 2;
      const int sl0 = (l0 & ~7) | ((l0 & 7) ^ (R & 7));
      const int l1 = l0 + 1;
      const int sl1 = (l1 & ~7) | ((l1 & 7) ^ (R & 7));
      const f32x4 fa = *(const f32x4*)(ab + sl0 * 16);
      const f32x4 fb = *(const f32x4*)(ab + sl1 * 16);
      bf16x8 ahi, alo;
      split8(fa, fb, ahi, alo);
      acc = __builtin_amdgcn_mfma_f32_16x16x32_bf16(ahi, wh[s], acc, 0, 0, 0);
      acc = __builtin_amdgcn_mfma_f32_16x16x32_bf16(alo, wh[s], acc, 0, 0, 0);
      acc = __builtin_amdgcn_mfma_f32_16x16x32_bf16(ahi, wl[s], acc, 0, 0, 0);
    }
    LGKM0;                                              // my ds_reads done
    __builtin_amdgcn_s_barrier();                       // (2) compute done

    // combine ksub halves in lt: D frag -> row (lane>>4)*4+j, col cb*16+(lane&15)
    const int colb = cb * 16 + (lane & 15);
    const int rowb = (lane >> 4) * 4;
    if (ksub == 0) {
#pragma unroll
      for (int j = 0; j < 4; ++j) lt[rowb + j][colb] = acc[j];
    }
    LGKM0;                                              // ksub0 writes VISIBLE
    __builtin_amdgcn_s_barrier();                       // (3) ksub0 written
    if (ksub == 1) {
#pragma unroll
      for (int j = 0; j < 4; ++j) lt[rowb + j][colb] += acc[j];
    }
    LGKM0;                                              // ksub1 adds VISIBLE
    __builtin_amdgcn_s_barrier();                       // (4) tile complete

    // cooperative store: 1024 floats -> partials[kseg][row][e]
    const int row0p = row_base + p * PROWS;
#pragma unroll
    for (int i = 0; i < 2; ++i) {
      const int idx = i * GTHR + t;
      const int r = idx >> 6, e = idx & 63;
      part[((size_t)kseg * B_ROWS + row0p + r) * E_EXP + e] = lt[r][e];
    }
  }
#undef ISSUE
#undef LGKM0
}

// reduce the 8 partials, softmax, top-2 (+near-tie flagging), psum/cnt.
__global__ __launch_bounds__(NTHR) void epilogue(
    const float* __restrict__ part, float* __restrict__ out,
    float* __restrict__ psum, unsigned int* __restrict__ cnt,
    int* __restrict__ flagcnt, int* __restrict__ flaglist) {
  __shared__ float pcol[E_EXP];
  __shared__ unsigned int scnt[E_EXP];

  const int t = threadIdx.x, lane = t & 63, wv = t >> 6;
  const int row0 = blockIdx.x * 64;     // 64 rows/block, 256 blocks

  if (t < E_EXP) { scnt[t] = 0; pcol[t] = 0.f; }
  __syncthreads();

#pragma unroll
  for (int j = 0; j < 8; ++j) {
    const int row = row0 + wv * 8 + j;
    float lg = 0.f;
#pragma unroll
    for (int s = 0; s < NSPLIT; ++s)
      lg += part[((size_t)s * B_ROWS + row) * E_EXP + lane];

    const float m  = wave_max64(lg);
    const float p  = __expf(lg - m);
    const float ss = wave_sum64(p);
    atomicAdd(&pcol[lane], p / ss);

    float v1; int i1; wave_argmax64(lg, lane, v1, i1);
    const float lm1 = (lane == i1) ? -INFINITY : lg;
    float v2; int i2; wave_argmax64(lm1, lane, v2, i2);
    const float lm2 = (lane == i2) ? -INFINITY : lm1;
    float v3; int i3; wave_argmax64(lm2, lane, v3, i3);
    if (lane == 0) {
      const float ex = expf(v2 - v1);
      out[row * 2 + 0] = 1.f / (1.f + ex);
      out[row * 2 + 1] = ex / (1.f + ex);
      out[2 * B_ROWS + row * 2 + 0] = (float)i1;
      out[2 * B_ROWS + row * 2 + 1] = (float)i2;
      atomicAdd(&scnt[i1], 1u);
      atomicAdd(&scnt[i2], 1u);
      if (v1 - v2 < GAPTHR || v2 - v3 < GAPTHR) {
        int fi = atomicAdd(flagcnt, 1);
        if (fi < FLAGCAP) flaglist[fi] = row;
      }
    }
  }
  __syncthreads();
  if (t < E_EXP) {
    atomicAdd(&psum[t], pcol[t]);
    const unsigned int c = scnt[t];
    if (c) atomicAdd(&cnt[t], c);
  }
}

// exact fp64 recompute of flagged (near-tie) rows; block 0 also computes aux.
__global__ __launch_bounds__(256) void cleanup(
    const float* __restrict__ rf, const float* __restrict__ gw,
    const int* __restrict__ flagcnt, const int* __restrict__ flaglist,
    const float* __restrict__ psum, const unsigned int* __restrict__ cnt,
    float* __restrict__ out) {
  __shared__ double sm[256];
  const int t = threadIdx.x;
  if (blockIdx.x == 0 && t < 64) {
    const float f = (float)cnt[t] / (float)(B_ROWS * 2);
    const float P = psum[t] / (float)B_ROWS;
    float v = wave_sum64(f * P);
    if (t == 0) out[4 * B_ROWS] = (float)E_EXP * v;
  }
  const int nf = min(*flagcnt, FLAGCAP);
  for (int fi = blockIdx.x; fi < nf; fi += gridDim.x) {
    const int row = flaglist[fi];
    const int e = t & 63, seg = t >> 6;
    const float* a = rf + (size_t)row * D_DIM + seg * 1024;
    const float* w = gw + (size_t)e * D_DIM + seg * 1024;
    double p0 = 0.0, p1 = 0.0, p2 = 0.0, p3 = 0.0;
    for (int k = 0; k < 1024; k += 4) {
      p0 = fma((double)a[k + 0], (double)w[k + 0], p0);
      p1 = fma((double)a[k + 1], (double)w[k + 1], p1);
      p2 = fma((double)a[k + 2], (double)w[k + 2], p2);
      p3 = fma((double)a[k + 3], (double)w[k + 3], p3);
    }
    sm[t] = (p0 + p1) + (p2 + p3);
    __syncthreads();
    if (t < 64) {
      const double l = sm[t] + sm[64 + t] + sm[128 + t] + sm[192 + t];
      double v = l; int ii = t;
#pragma unroll
      for (int m = 32; m >= 1; m >>= 1) {
        double ov = __shfl_xor(v, m, 64); int oi = __shfl_xor(ii, m, 64);
        if (ov > v || (ov == v && oi < ii)) { v = ov; ii = oi; }
      }
      const double v1 = v; const int i1 = ii;
      const double lm = (t == i1) ? -1e300 : l;
      v = lm; ii = t;
#pragma unroll
      for (int m = 32; m >= 1; m >>= 1) {
        double ov = __shfl_xor(v, m, 64); int oi = __shfl_xor(ii, m, 64);
        if (ov > v || (ov == v && oi < ii)) { v = ov; ii = oi; }
      }
      const double v2 = v; const int i2 = ii;
      if (t == 0) {
        const double ex = exp(v2 - v1);
        out[row * 2 + 0] = (float)(1.0 / (1.0 + ex));
        out[row * 2 + 1] = (float)(ex / (1.0 + ex));
        out[2 * B_ROWS + row * 2 + 0] = (float)i1;
        out[2 * B_ROWS + row * 2 + 1] = (float)i2;
      }
    }
    __syncthreads();
  }
}

extern "C" void kernel_launch(void* const* d_in, const int* in_sizes, int n_in,
                              void* d_out, int out_size, void* d_ws, size_t ws_size,
                              hipStream_t stream) {
  const float* rf = (const float*)d_in[0];
  const float* gw = (const float*)d_in[1];
  float* out = (float*)d_out;
  float* psum = (float*)d_ws;
  unsigned int* cnt = (unsigned int*)((char*)d_ws + 256);
  int* flagcnt = (int*)((char*)d_ws + 512);
  int* flaglist = (int*)((char*)d_ws + 768);
  char* wsW = (char*)d_ws + (1u << 20);
  float* part = (float*)((char*)d_ws + (2u << 20));

  wsplit<<<D_DIM / 32, NTHR, 0, stream>>>(gw, wsW, (unsigned int*)d_ws);
  gemm_partial<<<NSPLIT * (B_ROWS / (PROWS * NPANEL)), GTHR, 0, stream>>>(rf, wsW, part);
  epilogue<<<B_ROWS / 64, NTHR, 0, stream>>>(part, out, psum, cnt, flagcnt, flaglist);
  cleanup<<<64, 256, 0, stream>>>(rf, gw, flagcnt, flaglist, psum, cnt, out);
}

// Round 20
// 222.319 us; speedup vs baseline: 1.1592x; 1.0061x over previous
//
#include <hip/hip_runtime.h>
#include <math.h>

// TopKRouter: logits = rf @ gw^T, softmax, top-2, aux load-balance loss.
// rf: [16384, 4096] f32, gw: [64, 4096] f32.
// out (f32 flat): weights [0,32768) | indices-as-float [32768,65536) | aux [65536]
//
// R19 = R13 (depth-2 pipelined ring, 64-row x KSEG-512 blocks, counted vmcnt)
// + two isolated changes probing the "rf reads capped ~1.7 TB/s by L3-hit
// path" theory (every R7-R18 structure converged there; FETCH ~139MB < 256MB
// shows L3 absorbs rf):
//  (1) A-loads use NT cache policy (aux=2 on global_load_lds) -> no L3/L2
//      allocation -> steady-state replays stream rf from HBM at ~6.3 TB/s.
//  (2) XCD-aligned split-K: ks = blockIdx&7 (8 ksegs = 8 XCDs) -> each XCD's
//      L2 privately caches its kseg's 128 KB W slice (W reads L2-local).
// ws: [0,256) psum | [256,512) cnt | [512,516) flagcnt | [768,+32K) flaglist
//     | [1M, +1MB) W frag stream | [2M, +32MB) partials [8][16384][64].

typedef __attribute__((ext_vector_type(8))) short bf16x8;
typedef __attribute__((ext_vector_type(4))) float f32x4;

constexpr int B_ROWS  = 16384;
constexpr int D_DIM   = 4096;
constexpr int E_EXP   = 64;
constexpr int NTHR    = 512;              // wsplit/epilogue threads
constexpr int GTHR    = 256;              // gemm threads (4 waves)
constexpr int TM      = 64;               // rows per gemm block
constexpr int KSEG    = 512;              // k-range per gemm block
constexpr int NSPLIT  = D_DIM / KSEG;     // 8
constexpr int NS      = KSEG / 32;        // 16 k-steps
constexpr int FLAGCAP = 8192;
constexpr float GAPTHR = 1e-3f;

__device__ __forceinline__ float wave_max64(float v) {
#pragma unroll
  for (int m = 32; m >= 1; m >>= 1) v = fmaxf(v, __shfl_xor(v, m, 64));
  return v;
}
__device__ __forceinline__ float wave_sum64(float v) {
#pragma unroll
  for (int m = 32; m >= 1; m >>= 1) v += __shfl_xor(v, m, 64);
  return v;
}
// argmax over 64 lanes; ties -> smaller index (matches jax.lax.top_k)
__device__ __forceinline__ void wave_argmax64(float v, int i, float& mv, int& mi) {
#pragma unroll
  for (int m = 32; m >= 1; m >>= 1) {
    float ov = __shfl_xor(v, m, 64);
    int   oi = __shfl_xor(i, m, 64);
    if (ov > v || (ov == v && oi < i)) { v = ov; i = oi; }
  }
  mv = v; mi = i;
}

// async global->LDS; cached (for W, reused across blocks)
__device__ __forceinline__ void async_copy16(void* lds_dst, const void* g_src) {
  auto g = (const __attribute__((address_space(1))) char*)(g_src);
  auto l = (__attribute__((address_space(3))) char*)(lds_dst);
  __builtin_amdgcn_global_load_lds(g, l, 16, 0, 0);
}
// async global->LDS; NT policy (for A: streamed once, don't pollute L2/L3)
__device__ __forceinline__ void async_copy16_nt(void* lds_dst, const void* g_src) {
  auto g = (const __attribute__((address_space(1))) char*)(g_src);
  auto l = (__attribute__((address_space(3))) char*)(lds_dst);
  __builtin_amdgcn_global_load_lds(g, l, 16, 0, 2 /* CPol NT */);
}

// trunc-split 8 fp32 -> hi/lo bf16 frags (f = hi + rem exactly at bf16 precision)
__device__ __forceinline__ void split8(const f32x4 a, const f32x4 b, bf16x8& hi, bf16x8& lo) {
  float f[8] = {a[0], a[1], a[2], a[3], b[0], b[1], b[2], b[3]};
#pragma unroll
  for (int i = 0; i < 8; ++i) {
    unsigned int u = __float_as_uint(f[i]);
    hi[i] = (short)(u >> 16);
    float rem = f[i] - __uint_as_float(u & 0xffff0000u);
    lo[i] = (short)(__float_as_uint(rem) >> 16);
  }
}

// W pre-split: gw [64][4096] f32 -> frag stream [n=k/32][cb][h][lane][16B].
// B-frag (mfma_f32_16x16x32_bf16): lane l elem i <-> B[k=(l>>4)*8+i][col=l&15].
// Block 0 also zeroes the ws header (psum/cnt/flagcnt).
__global__ __launch_bounds__(NTHR) void wsplit(const float* __restrict__ gw,
                                               char* __restrict__ wsW,
                                               unsigned int* __restrict__ hdr) {
  const int n = blockIdx.x;          // 128 k-steps
  const int t = threadIdx.x;
  if (n == 0 && t < 192) hdr[t] = 0u;
  const int lane = t & 63, h = (t >> 6) & 1, wc = t >> 7;
  const int col = wc * 16 + (lane & 15);
  const int k0  = n * 32 + (lane >> 4) * 8;
  const float* src = gw + (size_t)col * D_DIM + k0;
  union { unsigned short us[8]; uint4 v; } pk;
#pragma unroll
  for (int i = 0; i < 8; ++i) {
    float f = src[i];
    unsigned int u = __float_as_uint(f);
    if (h == 0) {
      pk.us[i] = (unsigned short)(u >> 16);
    } else {
      float rem = f - __uint_as_float(u & 0xffff0000u);
      pk.us[i] = (unsigned short)(__float_as_uint(rem) >> 16);
    }
  }
  *(uint4*)(wsW + (size_t)n * 8192 + (size_t)t * 16) = pk.v;
}

__global__ __launch_bounds__(GTHR) void gemm_partial(
    const float* __restrict__ rf, const char* __restrict__ wsW,
    float* __restrict__ part) {
  // 3 ring buffers of [A 8K | W 8K] = 48 KB -> 3 blocks/CU
  __shared__ char lds[3 * 16384] __attribute__((aligned(16)));

  const int t = threadIdx.x, lane = t & 63, wv = t >> 6;
  // XCD-aligned: kseg = blockIdx&7 -> all blocks on one XCD share one kseg's
  // 128 KB W slice in that XCD's L2.
  const int ks = blockIdx.x & 7, rb = blockIdx.x >> 3;
  const int row0 = rb * TM;

  // staging: A tile [64 rows][8 x 16B slots]; LDS linear, source slot
  // pre-swizzled (s_glob = s_lds ^ (row&7)) for conflict-free frag reads.
  int goffA[2];
#pragma unroll
  for (int j = 0; j < 2; ++j) {
    const int q = j * GTHR + t;
    const int row = q >> 3, sl = q & 7;
    goffA[j] = (row0 + row) * D_DIM + ks * KSEG + ((sl ^ (row & 7)) << 2);
  }
  const char* wsrc = wsW + (size_t)(ks * NS) * 8192;

  // compute-side A frag read offsets (logical slot s -> LDS slot s^(row&7))
  const int rr  = wv * 16 + (lane & 15);
  const int s0  = (lane >> 4) * 2;
  const int a00 = rr * 128 + ((s0 ^ (rr & 7)) << 4);
  const int a01 = rr * 128 + (((s0 + 1) ^ (rr & 7)) << 4);

  f32x4 acc[4] = {{0.f,0.f,0.f,0.f},{0.f,0.f,0.f,0.f},{0.f,0.f,0.f,0.f},{0.f,0.f,0.f,0.f}};

#define ISSUE(nn)                                                            \
  {                                                                          \
    char* b_ = lds + ((nn) % 3) * 16384;                                     \
    async_copy16_nt(b_ + t * 16, rf + goffA[0] + (nn) * 32);                 \
    async_copy16_nt(b_ + (GTHR + t) * 16, rf + goffA[1] + (nn) * 32);        \
    async_copy16(b_ + 8192 + t * 16, wsrc + (size_t)(nn) * 8192 + t * 16);   \
    async_copy16(b_ + 8192 + (GTHR + t) * 16,                                \
                 wsrc + (size_t)(nn) * 8192 + (GTHR + t) * 16);              \
  }

  ISSUE(0);
  ISSUE(1);
#pragma unroll
  for (int n = 0; n < NS; ++n) {
    if (n + 2 < NS) {
      ISSUE(n + 2);                                     // depth-2 lookahead
      asm volatile("s_waitcnt vmcnt(8)" ::: "memory");  // tile n resident (mine)
    } else if (n + 1 < NS) {
      asm volatile("s_waitcnt vmcnt(4)" ::: "memory");
    } else {
      asm volatile("s_waitcnt vmcnt(0)" ::: "memory");
    }
    __builtin_amdgcn_s_barrier();                       // tile n resident (all)

    const char* ab = lds + (n % 3) * 16384;
    const char* wb = ab + 8192 + lane * 16;
    const f32x4 fl = *(const f32x4*)(ab + a00);
    const f32x4 fh = *(const f32x4*)(ab + a01);
    bf16x8 ahi, alo;
    split8(fl, fh, ahi, alo);
#pragma unroll
    for (int cb = 0; cb < 4; ++cb) {
      const bf16x8 whi = *(const bf16x8*)(wb + cb * 2048);
      const bf16x8 wlo = *(const bf16x8*)(wb + cb * 2048 + 1024);
      acc[cb] = __builtin_amdgcn_mfma_f32_16x16x32_bf16(ahi, whi, acc[cb], 0, 0, 0);
      acc[cb] = __builtin_amdgcn_mfma_f32_16x16x32_bf16(alo, whi, acc[cb], 0, 0, 0);
      acc[cb] = __builtin_amdgcn_mfma_f32_16x16x32_bf16(ahi, wlo, acc[cb], 0, 0, 0);
    }
    __builtin_amdgcn_s_barrier();                       // ring slot n%3 free
  }
#undef ISSUE

  // store partials: D frag -> row = wv*16 + (lane>>4)*4 + j, col = cb*16 + (lane&15)
  const int colb = lane & 15;
  const int rowb = (lane >> 4) * 4;
  float* dst = part + ((size_t)ks * B_ROWS + row0 + wv * 16 + rowb) * E_EXP + colb;
#pragma unroll
  for (int cb = 0; cb < 4; ++cb)
#pragma unroll
    for (int j = 0; j < 4; ++j)
      dst[(size_t)j * E_EXP + cb * 16] = acc[cb][j];
}

// reduce the 8 partials, softmax, top-2 (+near-tie flagging), psum/cnt.
__global__ __launch_bounds__(NTHR) void epilogue(
    const float* __restrict__ part, float* __restrict__ out,
    float* __restrict__ psum, unsigned int* __restrict__ cnt,
    int* __restrict__ flagcnt, int* __restrict__ flaglist) {
  __shared__ float pcol[E_EXP];
  __shared__ unsigned int scnt[E_EXP];

  const int t = threadIdx.x, lane = t & 63, wv = t >> 6;
  const int row0 = blockIdx.x * 64;     // 64 rows/block, 256 blocks

  if (t < E_EXP) { scnt[t] = 0; pcol[t] = 0.f; }
  __syncthreads();

#pragma unroll
  for (int j = 0; j < 8; ++j) {
    const int row = row0 + wv * 8 + j;
    float lg = 0.f;
#pragma unroll
    for (int s = 0; s < NSPLIT; ++s)
      lg += part[((size_t)s * B_ROWS + row) * E_EXP + lane];

    const float m  = wave_max64(lg);
    const float p  = __expf(lg - m);
    const float ss = wave_sum64(p);
    atomicAdd(&pcol[lane], p / ss);

    float v1; int i1; wave_argmax64(lg, lane, v1, i1);
    const float lm1 = (lane == i1) ? -INFINITY : lg;
    float v2; int i2; wave_argmax64(lm1, lane, v2, i2);
    const float lm2 = (lane == i2) ? -INFINITY : lm1;
    float v3; int i3; wave_argmax64(lm2, lane, v3, i3);
    if (lane == 0) {
      const float ex = expf(v2 - v1);
      out[row * 2 + 0] = 1.f / (1.f + ex);
      out[row * 2 + 1] = ex / (1.f + ex);
      out[2 * B_ROWS + row * 2 + 0] = (float)i1;
      out[2 * B_ROWS + row * 2 + 1] = (float)i2;
      atomicAdd(&scnt[i1], 1u);
      atomicAdd(&scnt[i2], 1u);
      if (v1 - v2 < GAPTHR || v2 - v3 < GAPTHR) {
        int fi = atomicAdd(flagcnt, 1);
        if (fi < FLAGCAP) flaglist[fi] = row;
      }
    }
  }
  __syncthreads();
  if (t < E_EXP) {
    atomicAdd(&psum[t], pcol[t]);
    const unsigned int c = scnt[t];
    if (c) atomicAdd(&cnt[t], c);
  }
}

// exact fp64 recompute of flagged (near-tie) rows; block 0 also computes aux.
__global__ __launch_bounds__(256) void cleanup(
    const float* __restrict__ rf, const float* __restrict__ gw,
    const int* __restrict__ flagcnt, const int* __restrict__ flaglist,
    const float* __restrict__ psum, const unsigned int* __restrict__ cnt,
    float* __restrict__ out) {
  __shared__ double sm[256];
  const int t = threadIdx.x;
  if (blockIdx.x == 0 && t < 64) {
    const float f = (float)cnt[t] / (float)(B_ROWS * 2);
    const float P = psum[t] / (float)B_ROWS;
    float v = wave_sum64(f * P);
    if (t == 0) out[4 * B_ROWS] = (float)E_EXP * v;
  }
  const int nf = min(*flagcnt, FLAGCAP);
  for (int fi = blockIdx.x; fi < nf; fi += gridDim.x) {
    const int row = flaglist[fi];
    const int e = t & 63, seg = t >> 6;
    const float* a = rf + (size_t)row * D_DIM + seg * 1024;
    const float* w = gw + (size_t)e * D_DIM + seg * 1024;
    double p0 = 0.0, p1 = 0.0, p2 = 0.0, p3 = 0.0;
    for (int k = 0; k < 1024; k += 4) {
      p0 = fma((double)a[k + 0], (double)w[k + 0], p0);
      p1 = fma((double)a[k + 1], (double)w[k + 1], p1);
      p2 = fma((double)a[k + 2], (double)w[k + 2], p2);
      p3 = fma((double)a[k + 3], (double)w[k + 3], p3);
    }
    sm[t] = (p0 + p1) + (p2 + p3);
    __syncthreads();
    if (t < 64) {
      const double l = sm[t] + sm[64 + t] + sm[128 + t] + sm[192 + t];
      double v = l; int ii = t;
#pragma unroll
      for (int m = 32; m >= 1; m >>= 1) {
        double ov = __shfl_xor(v, m, 64); int oi = __shfl_xor(ii, m, 64);
        if (ov > v || (ov == v && oi < ii)) { v = ov; ii = oi; }
      }
      const double v1 = v; const int i1 = ii;
      const double lm = (t == i1) ? -1e300 : l;
      v = lm; ii = t;
#pragma unroll
      for (int m = 32; m >= 1; m >>= 1) {
        double ov = __shfl_xor(v, m, 64); int oi = __shfl_xor(ii, m, 64);
        if (ov > v || (ov == v && oi < ii)) { v = ov; ii = oi; }
      }
      const double v2 = v; const int i2 = ii;
      if (t == 0) {
        const double ex = exp(v2 - v1);
        out[row * 2 + 0] = (float)(1.0 / (1.0 + ex));
        out[row * 2 + 1] = (float)(ex / (1.0 + ex));
        out[2 * B_ROWS + row * 2 + 0] = (float)i1;
        out[2 * B_ROWS + row * 2 + 1] = (float)i2;
      }
    }
    __syncthreads();
  }
}

extern "C" void kernel_launch(void* const* d_in, const int* in_sizes, int n_in,
                              void* d_out, int out_size, void* d_ws, size_t ws_size,
                              hipStream_t stream) {
  const float* rf = (const float*)d_in[0];
  const float* gw = (const float*)d_in[1];
  float* out = (float*)d_out;
  float* psum = (float*)d_ws;
  unsigned int* cnt = (unsigned int*)((char*)d_ws + 256);
  int* flagcnt = (int*)((char*)d_ws + 512);
  int* flaglist = (int*)((char*)d_ws + 768);
  char* wsW = (char*)d_ws + (1u << 20);
  float* part = (float*)((char*)d_ws + (2u << 20));

  wsplit<<<D_DIM / 32, NTHR, 0, stream>>>(gw, wsW, (unsigned int*)d_ws);
  gemm_partial<<<NSPLIT * (B_ROWS / TM), GTHR, 0, stream>>>(rf, wsW, part);
  epilogue<<<B_ROWS / 64, NTHR, 0, stream>>>(part, out, psum, cnt, flagcnt, flaglist);
  cleanup<<<64, 256, 0, stream>>>(rf, gw, flagcnt, flaglist, psum, cnt, out);
}